// Round 1
// baseline (87.357 us; speedup 1.0000x reference)
//
#include <hip/hip_runtime.h>
#include <hip/hip_bf16.h>
#include <math.h>

#define N_ATOMS 1024
#define IN_F 64
#define H_DIM 32
#define NRBF 50
#define TILE 16           // 16x16 pair tile per block
#define NBLOCKS ((N_ATOMS / TILE) * (N_ATOMS / TILE))  // 4096

// ---------------- Kernel 1: hp = h @ W_fc  (1024x64 @ 64x32) ----------------
__global__ __launch_bounds__(256) void hp_kernel(
    const float* __restrict__ h, const float* __restrict__ W_fc,
    float* __restrict__ hp)
{
    int t = blockIdx.x * blockDim.x + threadIdx.x;   // 0 .. 32767
    if (t >= N_ATOMS * H_DIM) return;
    int i = t >> 5;        // row
    int o = t & 31;        // output feature
    float acc = 0.f;
    #pragma unroll 8
    for (int k = 0; k < IN_F; ++k)
        acc += h[i * IN_F + k] * W_fc[k * H_DIM + o];
    hp[i * H_DIM + o] = acc;
}

// ---------------- Kernel 2: per-pair computation -> per-block partial sums --
__global__ __launch_bounds__(256) void pair_kernel(
    const float* __restrict__ x, const float* __restrict__ hp,
    const float* __restrict__ W_edge, const float* __restrict__ means,
    const float* __restrict__ betas, const float* __restrict__ W1,
    const float* __restrict__ b1, const float* __restrict__ W2,
    const float* __restrict__ b2, float* __restrict__ partials)
{
    __shared__ float sxi[TILE][3], sxj[TILE][3];
    __shared__ float shpi[TILE][H_DIM + 1], shpj[TILE][H_DIM + 1];  // +1 pad: break bank conflicts
    __shared__ float swave[4];

    const int t = threadIdx.x;
    const int ti = blockIdx.x >> 6;     // 64 j-tiles per row of tiles
    const int tj = blockIdx.x & 63;
    const int i0 = ti * TILE;
    const int j0 = tj * TILE;

    // ---- stage x and hp tiles ----
    if (t < TILE * 3) {
        sxi[t / 3][t % 3] = x[(i0 + t / 3) * 3 + t % 3];
    } else if (t < TILE * 6) {
        int u = t - TILE * 3;
        sxj[u / 3][u % 3] = x[(j0 + u / 3) * 3 + u % 3];
    }
    for (int u = t; u < TILE * H_DIM; u += 256) {
        int r = u >> 5, c = u & 31;
        shpi[r][c] = hp[(i0 + r) * H_DIM + c];
        shpj[r][c] = hp[(j0 + r) * H_DIM + c];
    }
    __syncthreads();

    const int li = t >> 4;     // local i (0..15)
    const int lj = t & 15;     // local j (0..15)

    const float dx = sxj[lj][0] - sxi[li][0];
    const float dy = sxj[lj][1] - sxi[li][1];
    const float dz = sxj[lj][2] - sxi[li][2];
    const float s  = dx * dx + dy * dy + dz * dz;

    const float dist = s + 1e-8f;                 // relu(s)+eps, s>=0 always
    const float dn2  = s / (s + 1e-8f);           // ||delta_n||^2
    // cut = 0.5*(cos(pi*(2*dist/5 + 1)) + 1)
    const float cut  = 0.5f * (cosf((float)M_PI * (0.4f * dist + 1.0f)) + 1.0f);
    const float ed   = __expf(-dist);

    // ---- he = rbf @ W_edge ; rbf_k computed on the fly ----
    float he[H_DIM];
    #pragma unroll
    for (int hh = 0; hh < H_DIM; ++hh) he[hh] = 0.f;

    for (int k = 0; k < NRBF; ++k) {              // uniform loop -> scalar loads of weights
        const float d = ed - means[k];
        const float r = cut * __expf(-betas[k] * d * d);
        #pragma unroll
        for (int hh = 0; hh < H_DIM; ++hh)
            he[hh] += r * W_edge[k * H_DIM + hh];
    }

    // ---- cnorm[h] = ((hp_i[h]+hp_j[h]) * he[h])^2 * dn2 (reuse he[] in place) ----
    #pragma unroll
    for (int hh = 0; hh < H_DIM; ++hh) {
        const float tt = (shpi[li][hh] + shpj[lj][hh]) * he[hh];
        he[hh] = tt * tt * dn2;
    }

    // ---- a = cnorm @ W1 + b1 ; e = sigmoid(a) @ W2 + b2 ----
    float a[H_DIM];
    #pragma unroll
    for (int o = 0; o < H_DIM; ++o) a[o] = b1[o];
    for (int hh = 0; hh < H_DIM; ++hh) {          // uniform weight rows -> scalar loads
        const float c = he[hh];
        #pragma unroll
        for (int o = 0; o < H_DIM; ++o)
            a[o] += c * W1[hh * H_DIM + o];
    }
    float e = b2[0];
    #pragma unroll
    for (int o = 0; o < H_DIM; ++o)
        e += W2[o] / (1.f + __expf(-a[o]));

    // ---- block reduction (deterministic) ----
    float v = e;
    #pragma unroll
    for (int off = 32; off > 0; off >>= 1)
        v += __shfl_down(v, off);
    if ((t & 63) == 0) swave[t >> 6] = v;
    __syncthreads();
    if (t == 0)
        partials[blockIdx.x] = (swave[0] + swave[1]) + (swave[2] + swave[3]);
}

// ---------------- Kernel 3: final deterministic reduction -------------------
__global__ __launch_bounds__(256) void reduce_kernel(
    const float* __restrict__ partials, float* __restrict__ out)
{
    __shared__ float sm[256];
    const int t = threadIdx.x;
    float a = 0.f;
    for (int u = t; u < NBLOCKS; u += 256) a += partials[u];
    sm[t] = a;
    __syncthreads();
    for (int off = 128; off > 0; off >>= 1) {
        if (t < off) sm[t] += sm[t + off];
        __syncthreads();
    }
    if (t == 0) out[0] = sm[0];
}

extern "C" void kernel_launch(void* const* d_in, const int* in_sizes, int n_in,
                              void* d_out, int out_size, void* d_ws, size_t ws_size,
                              hipStream_t stream) {
    const float* h      = (const float*)d_in[0];
    const float* x      = (const float*)d_in[1];
    const float* W_fc   = (const float*)d_in[2];
    const float* W_edge = (const float*)d_in[3];
    const float* means  = (const float*)d_in[4];
    const float* betas  = (const float*)d_in[5];
    const float* W1     = (const float*)d_in[6];
    const float* b1     = (const float*)d_in[7];
    const float* W2     = (const float*)d_in[8];
    const float* b2     = (const float*)d_in[9];
    float* out = (float*)d_out;

    float* ws_partials = (float*)d_ws;                    // NBLOCKS floats
    float* ws_hp       = ws_partials + NBLOCKS;           // 1024*32 floats

    hp_kernel<<<(N_ATOMS * H_DIM + 255) / 256, 256, 0, stream>>>(h, W_fc, ws_hp);
    pair_kernel<<<NBLOCKS, 256, 0, stream>>>(x, ws_hp, W_edge, means, betas,
                                             W1, b1, W2, b2, ws_partials);
    reduce_kernel<<<1, 256, 0, stream>>>(ws_partials, out);
}

// Round 2
// 43.229 us; speedup vs baseline: 2.0208x; 2.0208x over previous
//
#include <hip/hip_runtime.h>
#include <hip/hip_bf16.h>
#include <math.h>

#define N_ATOMS 1024
#define IN_F 64
#define H_DIM 32
#define NRBF 50
#define TILE 16
#define NT (N_ATOMS / TILE)              // 64 tiles per dim
#define NBT (NT * (NT + 1) / 2)          // 2080 triangular tile-blocks
#define TBL 2048                         // G-table entries over ed in [0,1]

// ---------------- Kernel 1: hp = h @ W_fc  (1024x64 @ 64x32) ----------------
__global__ __launch_bounds__(256) void hp_kernel(
    const float* __restrict__ h, const float* __restrict__ W_fc,
    float* __restrict__ hp)
{
    int t = blockIdx.x * blockDim.x + threadIdx.x;   // 0 .. 32767
    if (t >= N_ATOMS * H_DIM) return;
    int i = t >> 5;
    int o = t & 31;
    float acc = 0.f;
    #pragma unroll 8
    for (int k = 0; k < IN_F; ++k)
        acc += h[i * IN_F + k] * W_fc[k * H_DIM + o];
    hp[i * H_DIM + o] = acc;
}

// ---------------- Kernel 1b: G table: G[idx][c] = sum_k exp(-b_k (ed-m_k)^2) W_edge[k][c]
__global__ __launch_bounds__(256) void table_kernel(
    const float* __restrict__ W_edge, const float* __restrict__ means,
    const float* __restrict__ betas, float* __restrict__ G)
{
    int t = blockIdx.x * blockDim.x + threadIdx.x;   // 0 .. TBL*4-1
    if (t >= TBL * 4) return;
    int idx = t >> 2;
    int c0  = (t & 3) * 8;
    float ed = (float)idx * (1.0f / (float)(TBL - 1));
    float acc[8];
    #pragma unroll
    for (int c = 0; c < 8; ++c) acc[c] = 0.f;
    for (int k = 0; k < NRBF; ++k) {                 // uniform -> scalar loads
        float d = ed - means[k];
        float w = __expf(-betas[k] * d * d);
        #pragma unroll
        for (int c = 0; c < 8; ++c)
            acc[c] += w * W_edge[k * H_DIM + c0 + c];
    }
    #pragma unroll
    for (int c = 0; c < 8; ++c) G[idx * H_DIM + c0 + c] = acc[c];
}

// ---------------- Kernel 2: per-pair (upper triangle only) ------------------
__global__ __launch_bounds__(256) void pair_kernel(
    const float* __restrict__ x, const float* __restrict__ hp,
    const float* __restrict__ G, const float* __restrict__ W1,
    const float* __restrict__ b1, const float* __restrict__ W2,
    const float* __restrict__ b2, float* __restrict__ partials)
{
    __shared__ float sxi[TILE][3], sxj[TILE][3];
    __shared__ float shpi[TILE][H_DIM + 4], shpj[TILE][H_DIM + 4];  // stride 36: 16B-aligned rows, conflict-free float4
    __shared__ float swave[4];

    const int t = threadIdx.x;
    const int b = blockIdx.x;

    // decode triangular tile index: row ti has tiles tj = ti..NT-1
    int ti = (int)(64.5f - sqrtf(64.5f * 64.5f - 2.0f * (float)b));
    if (ti < 0) ti = 0;
    if (ti > NT - 1) ti = NT - 1;
    while (ti > 0 && (ti * NT - ti * (ti - 1) / 2) > b) --ti;
    while (((ti + 1) * NT - (ti + 1) * ti / 2) <= b) ++ti;
    const int tj = ti + (b - (ti * NT - ti * (ti - 1) / 2));
    const int i0 = ti * TILE, j0 = tj * TILE;
    const bool diag = (ti == tj);

    // ---- stage tiles ----
    if (t < TILE * 3) {
        sxi[t / 3][t % 3] = x[(i0 + t / 3) * 3 + t % 3];
    } else if (t < TILE * 6) {
        int u = t - TILE * 3;
        sxj[u / 3][u % 3] = x[(j0 + u / 3) * 3 + u % 3];
    }
    for (int u = t; u < TILE * H_DIM; u += 256) {
        int r = u >> 5, c = u & 31;
        shpi[r][c] = hp[(i0 + r) * H_DIM + c];
        shpj[r][c] = hp[(j0 + r) * H_DIM + c];
    }
    __syncthreads();

    const int li = t >> 4;
    const int lj = t & 15;

    const float dx = sxj[lj][0] - sxi[li][0];
    const float dy = sxj[lj][1] - sxi[li][1];
    const float dz = sxj[lj][2] - sxi[li][2];
    const float s  = dx * dx + dy * dy + dz * dz;

    const float dist = s + 1e-8f;
    const float dn2  = s / (s + 1e-8f);
    // cut = 0.5*(cos(pi*(0.4*dist+1))+1) = sin^2(0.2*pi*dist)
    const float sn   = __sinf(0.62831853f * dist);
    const float cut  = sn * sn;
    const float K    = dn2 * cut * cut;            // folded scale for cnorm
    const float ed   = __expf(-dist);

    // ---- he/cut = lerp(G, ed) ----
    float u  = ed * (float)(TBL - 1);
    int idx  = (int)u;
    if (idx > TBL - 2) idx = TBL - 2;
    const float fr = u - (float)idx;
    const float* __restrict__ r0 = G + idx * H_DIM;

    float g[H_DIM];
    #pragma unroll
    for (int q = 0; q < 8; ++q) {
        float4 a0 = *(const float4*)(r0 + q * 4);
        float4 a1 = *(const float4*)(r0 + H_DIM + q * 4);
        g[q*4+0] = a0.x + fr * (a1.x - a0.x);
        g[q*4+1] = a0.y + fr * (a1.y - a0.y);
        g[q*4+2] = a0.z + fr * (a1.z - a0.z);
        g[q*4+3] = a0.w + fr * (a1.w - a0.w);
    }

    // ---- cnorm[h] = ((hp_i+hp_j) * g)^2 * K  (in place in g) ----
    #pragma unroll
    for (int q = 0; q < 8; ++q) {
        float4 hi = *(const float4*)(&shpi[li][q * 4]);
        float4 hj = *(const float4*)(&shpj[lj][q * 4]);
        float t0 = (hi.x + hj.x) * g[q*4+0];
        float t1 = (hi.y + hj.y) * g[q*4+1];
        float t2 = (hi.z + hj.z) * g[q*4+2];
        float t3 = (hi.w + hj.w) * g[q*4+3];
        g[q*4+0] = t0 * t0 * K;
        g[q*4+1] = t1 * t1 * K;
        g[q*4+2] = t2 * t2 * K;
        g[q*4+3] = t3 * t3 * K;
    }

    // ---- a = cnorm @ W1 + b1 ; e = sigmoid(a) @ W2 + b2 ----
    float a[H_DIM];
    #pragma unroll
    for (int o = 0; o < H_DIM; ++o) a[o] = b1[o];
    for (int hh = 0; hh < H_DIM; ++hh) {           // uniform weight rows -> scalar loads
        const float c = g[hh];
        #pragma unroll
        for (int o = 0; o < H_DIM; ++o)
            a[o] += c * W1[hh * H_DIM + o];
    }
    float e = b2[0];
    #pragma unroll
    for (int o = 0; o < H_DIM; ++o) {
        const float tt = __expf(-a[o]);
        e += W2[o] * __builtin_amdgcn_rcpf(1.0f + tt);
    }

    // mask: diagonal tile keeps only i<j (i==j handled analytically)
    if (diag && li >= lj) e = 0.f;

    // ---- block reduction (deterministic) ----
    float v = e;
    #pragma unroll
    for (int off = 32; off > 0; off >>= 1)
        v += __shfl_down(v, off);
    if ((t & 63) == 0) swave[t >> 6] = v;
    __syncthreads();
    if (t == 0)
        partials[b] = (swave[0] + swave[1]) + (swave[2] + swave[3]);
}

// ---------------- Kernel 3: final deterministic reduction -------------------
__global__ __launch_bounds__(256) void reduce_kernel(
    const float* __restrict__ partials, const float* __restrict__ W2,
    const float* __restrict__ b1, const float* __restrict__ b2,
    float* __restrict__ out)
{
    __shared__ float sm[256];
    const int t = threadIdx.x;
    float a = 0.f;
    for (int u = t; u < NBT; u += 256) a += partials[u];
    sm[t] = a;
    __syncthreads();
    for (int off = 128; off > 0; off >>= 1) {
        if (t < off) sm[t] += sm[t + off];
        __syncthreads();
    }
    if (t == 0) {
        // diagonal: s=0 -> dn2=0 -> cnorm=0 -> a=b1
        float edg = b2[0];
        for (int o = 0; o < H_DIM; ++o)
            edg += W2[o] / (1.0f + __expf(-b1[o]));
        out[0] = 2.0f * sm[0] + (float)N_ATOMS * edg;
    }
}

extern "C" void kernel_launch(void* const* d_in, const int* in_sizes, int n_in,
                              void* d_out, int out_size, void* d_ws, size_t ws_size,
                              hipStream_t stream) {
    const float* h      = (const float*)d_in[0];
    const float* x      = (const float*)d_in[1];
    const float* W_fc   = (const float*)d_in[2];
    const float* W_edge = (const float*)d_in[3];
    const float* means  = (const float*)d_in[4];
    const float* betas  = (const float*)d_in[5];
    const float* W1     = (const float*)d_in[6];
    const float* b1     = (const float*)d_in[7];
    const float* W2     = (const float*)d_in[8];
    const float* b2     = (const float*)d_in[9];
    float* out = (float*)d_out;

    float* ws_partials = (float*)d_ws;                 // NBT floats (pad 2560)
    float* ws_hp       = ws_partials + 2560;           // 1024*32
    float* ws_G        = ws_hp + N_ATOMS * H_DIM;      // TBL*32

    hp_kernel<<<(N_ATOMS * H_DIM + 255) / 256, 256, 0, stream>>>(h, W_fc, ws_hp);
    table_kernel<<<(TBL * 4 + 255) / 256, 256, 0, stream>>>(W_edge, means, betas, ws_G);
    pair_kernel<<<NBT, 256, 0, stream>>>(x, ws_hp, ws_G, W1, b1, W2, b2, ws_partials);
    reduce_kernel<<<1, 256, 0, stream>>>(ws_partials, W2, b1, b2, out);
}

// Round 3
// 37.567 us; speedup vs baseline: 2.3253x; 1.1507x over previous
//
#include <hip/hip_runtime.h>
#include <hip/hip_bf16.h>
#include <math.h>

#define N_ATOMS 1024
#define IN_F 64
#define H_DIM 32
#define NRBF 50
#define TILE 16
#define NT (N_ATOMS / TILE)              // 64 tiles per dim
#define NBT (NT * (NT + 1) / 2)          // 2080 triangular tile-blocks
#define TBL 2048                         // G-table entries over ed in [0,1]
#define SASTR 40                         // LDS A stride (bf16 elems): 80B rows -> conflict-free

typedef short bf16x8 __attribute__((ext_vector_type(8)));
typedef float f32x4  __attribute__((ext_vector_type(4)));

static __device__ __forceinline__ unsigned short f2bf(float f) {
    unsigned int u = __float_as_uint(f);
    u += 0x7fffu + ((u >> 16) & 1u);     // round-to-nearest-even
    return (unsigned short)(u >> 16);
}

// ---------------- Kernel 1: hp = h @ W_fc  (1024x64 @ 64x32) ----------------
__global__ __launch_bounds__(256) void hp_kernel(
    const float* __restrict__ h, const float* __restrict__ W_fc,
    float* __restrict__ hp)
{
    int t = blockIdx.x * blockDim.x + threadIdx.x;
    if (t >= N_ATOMS * H_DIM) return;
    int i = t >> 5;
    int o = t & 31;
    float acc = 0.f;
    #pragma unroll 8
    for (int k = 0; k < IN_F; ++k)
        acc += h[i * IN_F + k] * W_fc[k * H_DIM + o];
    hp[i * H_DIM + o] = acc;
}

// ---------------- Kernel 1b: G table --------------------------------------
__global__ __launch_bounds__(256) void table_kernel(
    const float* __restrict__ W_edge, const float* __restrict__ means,
    const float* __restrict__ betas, float* __restrict__ G)
{
    int t = blockIdx.x * blockDim.x + threadIdx.x;
    if (t >= TBL * 4) return;
    int idx = t >> 2;
    int c0  = (t & 3) * 8;
    float ed = (float)idx * (1.0f / (float)(TBL - 1));
    float acc[8];
    #pragma unroll
    for (int c = 0; c < 8; ++c) acc[c] = 0.f;
    for (int k = 0; k < NRBF; ++k) {
        float d = ed - means[k];
        float w = __expf(-betas[k] * d * d);
        #pragma unroll
        for (int c = 0; c < 8; ++c)
            acc[c] += w * W_edge[k * H_DIM + c0 + c];
    }
    #pragma unroll
    for (int c = 0; c < 8; ++c) G[idx * H_DIM + c0 + c] = acc[c];
}

// ---------------- Kernel 2: per-pair tiles, MFMA for cnorm @ W1 -------------
__global__ __launch_bounds__(256) void pair_kernel(
    const float* __restrict__ x, const float* __restrict__ hp,
    const float* __restrict__ G, const float* __restrict__ W1,
    const float* __restrict__ b1, const float* __restrict__ W2,
    const float* __restrict__ b2, float* __restrict__ partials)
{
    __shared__ float sxi[TILE][3], sxj[TILE][3];
    __shared__ float shpi[TILE][H_DIM + 4], shpj[TILE][H_DIM + 4];
    __shared__ unsigned short sA[256 * SASTR];   // 256 pair-rows x 32 bf16, stride 40
    __shared__ float swave[4];

    const int t = threadIdx.x;
    const int b = blockIdx.x;
    const int lane = t & 63;

    // decode triangular tile index
    int ti = (int)(64.5f - sqrtf(64.5f * 64.5f - 2.0f * (float)b));
    if (ti < 0) ti = 0;
    if (ti > NT - 1) ti = NT - 1;
    while (ti > 0 && (ti * NT - ti * (ti - 1) / 2) > b) --ti;
    while (((ti + 1) * NT - (ti + 1) * ti / 2) <= b) ++ti;
    const int tj = ti + (b - (ti * NT - ti * (ti - 1) / 2));
    const int i0 = ti * TILE, j0 = tj * TILE;
    const float wgt = (ti == tj) ? 1.0f : 2.0f;

    // ---- per-lane B fragments for W1 (K=32, N=32 -> 2 col-subtiles) --------
    // B layout (16x16x32 bf16): lane holds B[k=(lane>>4)*8+j][col=lane&15]
    const int c0f = lane & 15;
    const int kb  = (lane >> 4) * 8;
    bf16x8 bfrag[2];
    float b1v[2], w2v[2];
    #pragma unroll
    for (int ct = 0; ct < 2; ++ct) {
        #pragma unroll
        for (int j = 0; j < 8; ++j)
            bfrag[ct][j] = (short)f2bf(W1[(kb + j) * H_DIM + c0f + 16 * ct]);
        b1v[ct] = b1[c0f + 16 * ct];
        w2v[ct] = W2[c0f + 16 * ct];
    }
    const float b2s = b2[0];

    // ---- stage x and hp tiles ----
    if (t < TILE * 3) {
        sxi[t / 3][t % 3] = x[(i0 + t / 3) * 3 + t % 3];
    } else if (t < TILE * 6) {
        int u = t - TILE * 3;
        sxj[u / 3][u % 3] = x[(j0 + u / 3) * 3 + u % 3];
    }
    for (int u = t; u < TILE * H_DIM; u += 256) {
        int r = u >> 5, c = u & 31;
        shpi[r][c] = hp[(i0 + r) * H_DIM + c];
        shpj[r][c] = hp[(j0 + r) * H_DIM + c];
    }
    __syncthreads();

    const int li = t >> 4;
    const int lj = t & 15;

    const float dx = sxj[lj][0] - sxi[li][0];
    const float dy = sxj[lj][1] - sxi[li][1];
    const float dz = sxj[lj][2] - sxi[li][2];
    const float s  = dx * dx + dy * dy + dz * dz;

    const float dist = s + 1e-8f;
    const float dn2  = s / (s + 1e-8f);        // 0 exactly when i==j
    const float sn   = __sinf(0.62831853f * dist);
    const float cut  = sn * sn;
    const float K    = dn2 * cut * cut;
    const float ed   = __expf(-dist);

    // ---- g = lerp(G, ed) : he/cut ----
    float u  = ed * (float)(TBL - 1);
    int idx  = (int)u;
    if (idx > TBL - 2) idx = TBL - 2;
    const float fr = u - (float)idx;
    const float* __restrict__ r0 = G + idx * H_DIM;

    float g[H_DIM];
    #pragma unroll
    for (int q = 0; q < 8; ++q) {
        float4 a0 = *(const float4*)(r0 + q * 4);
        float4 a1 = *(const float4*)(r0 + H_DIM + q * 4);
        g[q*4+0] = a0.x + fr * (a1.x - a0.x);
        g[q*4+1] = a0.y + fr * (a1.y - a0.y);
        g[q*4+2] = a0.z + fr * (a1.z - a0.z);
        g[q*4+3] = a0.w + fr * (a1.w - a0.w);
    }

    // ---- cnorm[h] = ((hp_i+hp_j) * g)^2 * K -> bf16 -> LDS row t ----
    #pragma unroll
    for (int q = 0; q < 8; ++q) {
        float4 hi = *(const float4*)(&shpi[li][q * 4]);
        float4 hj = *(const float4*)(&shpj[lj][q * 4]);
        float t0 = (hi.x + hj.x) * g[q*4+0];
        float t1 = (hi.y + hj.y) * g[q*4+1];
        float t2 = (hi.z + hj.z) * g[q*4+2];
        float t3 = (hi.w + hj.w) * g[q*4+3];
        bf16x8* dst = (bf16x8*)&sA[t * SASTR + q * 4];
        // accumulate two q iterations into one 16B write: do manual pairing below
        (void)dst;
        g[q*4+0] = t0 * t0 * K;
        g[q*4+1] = t1 * t1 * K;
        g[q*4+2] = t2 * t2 * K;
        g[q*4+3] = t3 * t3 * K;
    }
    #pragma unroll
    for (int q = 0; q < 4; ++q) {          // 4 x 16B writes, 80B row stride
        bf16x8 pk;
        #pragma unroll
        for (int j = 0; j < 8; ++j)
            pk[j] = (short)f2bf(g[q * 8 + j]);
        *(bf16x8*)&sA[t * SASTR + q * 8] = pk;
    }
    __syncthreads();

    // ---- MFMA: a = cnorm @ W1 ; epilogue sigma/W2 sum ----------------------
    // A layout (16x16x32 bf16): lane holds A[row=lane&15][k=(lane>>4)*8+j]
    const int w = t >> 6;
    float p = 0.f;
    #pragma unroll
    for (int rt = 0; rt < 4; ++rt) {
        const int row = w * 64 + rt * 16 + (lane & 15);
        bf16x8 afrag = *(const bf16x8*)&sA[row * SASTR + kb];
        #pragma unroll
        for (int ct = 0; ct < 2; ++ct) {
            f32x4 acc = {0.f, 0.f, 0.f, 0.f};
            acc = __builtin_amdgcn_mfma_f32_16x16x32_bf16(afrag, bfrag[ct], acc, 0, 0, 0);
            #pragma unroll
            for (int r = 0; r < 4; ++r) {
                const float aval = acc[r] + b1v[ct];
                p += w2v[ct] * __builtin_amdgcn_rcpf(1.0f + __expf(-aval));
            }
        }
    }

    // ---- block reduction (deterministic) ----
    float v = p;
    #pragma unroll
    for (int off = 32; off > 0; off >>= 1)
        v += __shfl_down(v, off);
    if ((t & 63) == 0) swave[t >> 6] = v;
    __syncthreads();
    if (t == 0)
        partials[b] = wgt * (((swave[0] + swave[1]) + (swave[2] + swave[3]))
                             + 256.0f * b2s);
}

// ---------------- Kernel 3: final deterministic reduction -------------------
__global__ __launch_bounds__(256) void reduce_kernel(
    const float* __restrict__ partials, float* __restrict__ out)
{
    __shared__ float sm[256];
    const int t = threadIdx.x;
    float a = 0.f;
    for (int u = t; u < NBT; u += 256) a += partials[u];
    sm[t] = a;
    __syncthreads();
    for (int off = 128; off > 0; off >>= 1) {
        if (t < off) sm[t] += sm[t + off];
        __syncthreads();
    }
    if (t == 0) out[0] = sm[0];
}

extern "C" void kernel_launch(void* const* d_in, const int* in_sizes, int n_in,
                              void* d_out, int out_size, void* d_ws, size_t ws_size,
                              hipStream_t stream) {
    const float* h      = (const float*)d_in[0];
    const float* x      = (const float*)d_in[1];
    const float* W_fc   = (const float*)d_in[2];
    const float* W_edge = (const float*)d_in[3];
    const float* means  = (const float*)d_in[4];
    const float* betas  = (const float*)d_in[5];
    const float* W1     = (const float*)d_in[6];
    const float* b1     = (const float*)d_in[7];
    const float* W2     = (const float*)d_in[8];
    const float* b2     = (const float*)d_in[9];
    float* out = (float*)d_out;

    float* ws_partials = (float*)d_ws;                 // NBT floats (pad 2560)
    float* ws_hp       = ws_partials + 2560;           // 1024*32
    float* ws_G        = ws_hp + N_ATOMS * H_DIM;      // TBL*32

    hp_kernel<<<(N_ATOMS * H_DIM + 255) / 256, 256, 0, stream>>>(h, W_fc, ws_hp);
    table_kernel<<<(TBL * 4 + 255) / 256, 256, 0, stream>>>(W_edge, means, betas, ws_G);
    pair_kernel<<<NBT, 256, 0, stream>>>(x, ws_hp, ws_G, W1, b1, W2, b2, ws_partials);
    reduce_kernel<<<1, 256, 0, stream>>>(ws_partials, out);
}

// Round 4
// 34.500 us; speedup vs baseline: 2.5321x; 1.0889x over previous
//
#include <hip/hip_runtime.h>
#include <hip/hip_bf16.h>
#include <math.h>

#define N_ATOMS 1024
#define IN_F 64
#define H_DIM 32
#define NRBF 50
#define TILE 16
#define NT 64                 // tiles per dim
#define NBT 2080              // triangular tile count
#define TBL 2048              // G-table entries
#define GRID_PAIR 1040        // each block does 2 tiles
#define SASTR 40              // LDS A row stride in bf16 (80B rows)

typedef short bf16x8 __attribute__((ext_vector_type(8)));
typedef float f32x4  __attribute__((ext_vector_type(4)));

static __device__ __forceinline__ unsigned short f2bf(float f) {
    unsigned int u = __float_as_uint(f);
    u += 0x7fffu + ((u >> 16) & 1u);     // RNE
    return (unsigned short)(u >> 16);
}

// ---------------- Kernel 1: fused hp = h@W_fc  AND  G table -----------------
__global__ __launch_bounds__(256) void prep_kernel(
    const float* __restrict__ h, const float* __restrict__ W_fc,
    const float* __restrict__ W_edge, const float* __restrict__ means,
    const float* __restrict__ betas, float* __restrict__ hp,
    float* __restrict__ G)
{
    const int blk = blockIdx.x;
    const int t = threadIdx.x;
    if (blk < 128) {                       // hp part: 32768 threads
        int id = blk * 256 + t;
        int i = id >> 5, o = id & 31;
        float acc = 0.f;
        #pragma unroll 8
        for (int k = 0; k < IN_F; ++k)
            acc += h[i * IN_F + k] * W_fc[k * H_DIM + o];
        hp[i * H_DIM + o] = acc;
    } else {                               // table part: 8192 threads
        int id = (blk - 128) * 256 + t;
        int idx = id >> 2, c0 = (id & 3) * 8;
        float ed = (float)idx * (1.0f / (float)(TBL - 1));
        float acc[8];
        #pragma unroll
        for (int c = 0; c < 8; ++c) acc[c] = 0.f;
        for (int k = 0; k < NRBF; ++k) {   // uniform -> scalar loads
            float d = ed - means[k];
            float wv = __expf(-betas[k] * d * d);
            #pragma unroll
            for (int c = 0; c < 8; ++c)
                acc[c] += wv * W_edge[k * H_DIM + c0 + c];
        }
        #pragma unroll
        for (int c = 0; c < 8; ++c) G[idx * H_DIM + c0 + c] = acc[c];
    }
}

// ---------------- Kernel 2: pair tiles, 2 tiles per block -------------------
__global__ __launch_bounds__(256) void pair_kernel(
    const float* __restrict__ x, const float* __restrict__ hp,
    const float* __restrict__ G, const float* __restrict__ W1,
    const float* __restrict__ b1, const float* __restrict__ W2,
    float* __restrict__ partials)
{
    __shared__ float sxi[TILE][4], sxj[TILE][4];
    __shared__ float shpi[TILE][36], shpj[TILE][36];   // 144B rows, 16B-aligned
    __shared__ unsigned short sA[256 * SASTR];
    __shared__ float swave[4];

    const int t    = threadIdx.x;
    const int lane = t & 63;
    const int w    = t >> 6;
    const int c0f  = lane & 15;
    const int kb   = (lane >> 4) * 8;

    // hoisted W1/b1/W2 fragments (B layout: lane holds B[k=kb+j][col=c0f+16ct])
    bf16x8 bfrag[2];
    float b1v[2], w2v[2];
    #pragma unroll
    for (int ct = 0; ct < 2; ++ct) {
        #pragma unroll
        for (int j = 0; j < 8; ++j)
            bfrag[ct][j] = (short)f2bf(W1[(kb + j) * H_DIM + c0f + 16 * ct]);
        b1v[ct] = b1[c0f + 16 * ct];
        w2v[ct] = W2[c0f + 16 * ct];
    }

    const int li = t >> 4;
    const int lj = t & 15;
    float p = 0.f;

    for (int it = 0; it < 2; ++it) {
        const int b = blockIdx.x + it * GRID_PAIR;

        // decode triangular tile index (row-major upper triangle incl. diag)
        int ti = (int)(64.5f - sqrtf(64.5f * 64.5f - 2.0f * (float)b));
        ti = ti < 0 ? 0 : (ti > NT - 1 ? NT - 1 : ti);
        while ((ti + 1) * NT - ((ti + 1) * ti) / 2 <= b) ++ti;
        while (ti > 0 && ti * NT - (ti * (ti - 1)) / 2 > b) --ti;
        const int tj = ti + (b - (ti * NT - (ti * (ti - 1)) / 2));
        const int i0 = ti * TILE, j0 = tj * TILE;
        const float wgt = (ti == tj) ? 1.0f : 2.0f;

        if (it) __syncthreads();           // WAR before restaging

        // stage hp tiles (vectorized: 1 float4 per thread) and x tiles
        if (t < 128) {
            int r = t >> 3, c = t & 7;
            *(float4*)&shpi[r][c * 4] = *(const float4*)&hp[(i0 + r) * H_DIM + c * 4];
        } else {
            int u = t - 128, r = u >> 3, c = u & 7;
            *(float4*)&shpj[r][c * 4] = *(const float4*)&hp[(j0 + r) * H_DIM + c * 4];
        }
        if (t < TILE) {
            sxi[t][0] = x[(i0 + t) * 3];
            sxi[t][1] = x[(i0 + t) * 3 + 1];
            sxi[t][2] = x[(i0 + t) * 3 + 2];
        } else if (t < 2 * TILE) {
            int u = t - TILE;
            sxj[u][0] = x[(j0 + u) * 3];
            sxj[u][1] = x[(j0 + u) * 3 + 1];
            sxj[u][2] = x[(j0 + u) * 3 + 2];
        }
        __syncthreads();

        const float dx = sxj[lj][0] - sxi[li][0];
        const float dy = sxj[lj][1] - sxi[li][1];
        const float dz = sxj[lj][2] - sxi[li][2];
        const float s  = dx * dx + dy * dy + dz * dz;

        const float dist = s + 1e-8f;
        const float dn2  = s / (s + 1e-8f);          // exactly 0 on diagonal
        const float sn   = __sinf(0.62831853f * dist);
        const float K    = dn2 * (sn * sn) * (sn * sn);  // dn2*cut^2
        const float ed   = __expf(-dist);

        float uu = ed * (float)(TBL - 1);
        int idx  = (int)uu;
        if (idx > TBL - 2) idx = TBL - 2;
        const float fr = uu - (float)idx;
        const float* __restrict__ r0 = G + idx * H_DIM;

        // fused lerp -> cnorm -> bf16 pack -> LDS, 8 elems per chunk
        #pragma unroll
        for (int q = 0; q < 4; ++q) {
            float4 a0 = *(const float4*)(r0 + q * 8);
            float4 a1 = *(const float4*)(r0 + q * 8 + 4);
            float4 c0 = *(const float4*)(r0 + H_DIM + q * 8);
            float4 c1 = *(const float4*)(r0 + H_DIM + q * 8 + 4);
            float4 hi0 = *(const float4*)&shpi[li][q * 8];
            float4 hi1 = *(const float4*)&shpi[li][q * 8 + 4];
            float4 hj0 = *(const float4*)&shpj[lj][q * 8];
            float4 hj1 = *(const float4*)&shpj[lj][q * 8 + 4];
            float v0 = (hi0.x + hj0.x) * (a0.x + fr * (c0.x - a0.x));
            float v1 = (hi0.y + hj0.y) * (a0.y + fr * (c0.y - a0.y));
            float v2 = (hi0.z + hj0.z) * (a0.z + fr * (c0.z - a0.z));
            float v3 = (hi0.w + hj0.w) * (a0.w + fr * (c0.w - a0.w));
            float v4 = (hi1.x + hj1.x) * (a1.x + fr * (c1.x - a1.x));
            float v5 = (hi1.y + hj1.y) * (a1.y + fr * (c1.y - a1.y));
            float v6 = (hi1.z + hj1.z) * (a1.z + fr * (c1.z - a1.z));
            float v7 = (hi1.w + hj1.w) * (a1.w + fr * (c1.w - a1.w));
            bf16x8 pk;
            pk[0] = (short)f2bf(v0 * v0 * K);
            pk[1] = (short)f2bf(v1 * v1 * K);
            pk[2] = (short)f2bf(v2 * v2 * K);
            pk[3] = (short)f2bf(v3 * v3 * K);
            pk[4] = (short)f2bf(v4 * v4 * K);
            pk[5] = (short)f2bf(v5 * v5 * K);
            pk[6] = (short)f2bf(v6 * v6 * K);
            pk[7] = (short)f2bf(v7 * v7 * K);
            *(bf16x8*)&sA[t * SASTR + q * 8] = pk;
        }
        __syncthreads();   // sA visibility across lanes

        // MFMA: a = cnorm @ W1 ; epilogue sigmoid/W2, weighted accumulate
        #pragma unroll
        for (int rt = 0; rt < 4; ++rt) {
            const int row = w * 64 + rt * 16 + c0f;
            bf16x8 afrag = *(const bf16x8*)&sA[row * SASTR + kb];
            #pragma unroll
            for (int ct = 0; ct < 2; ++ct) {
                f32x4 acc = {0.f, 0.f, 0.f, 0.f};
                acc = __builtin_amdgcn_mfma_f32_16x16x32_bf16(afrag, bfrag[ct], acc, 0, 0, 0);
                #pragma unroll
                for (int r = 0; r < 4; ++r) {
                    const float av = acc[r] + b1v[ct];
                    p += wgt * w2v[ct] * __builtin_amdgcn_rcpf(1.0f + __expf(-av));
                }
            }
        }
    }

    // block reduction (deterministic)
    float v = p;
    #pragma unroll
    for (int off = 32; off > 0; off >>= 1)
        v += __shfl_down(v, off);
    if (lane == 0) swave[w] = v;
    __syncthreads();
    if (t == 0)
        partials[blockIdx.x] = (swave[0] + swave[1]) + (swave[2] + swave[3]);
}

// ---------------- Kernel 3: final deterministic reduction -------------------
__global__ __launch_bounds__(256) void reduce_kernel(
    const float* __restrict__ partials, const float* __restrict__ b2,
    float* __restrict__ out)
{
    __shared__ float sm[256];
    const int t = threadIdx.x;
    float a = 0.f;
    for (int u = t; u < GRID_PAIR; u += 256) a += partials[u];
    sm[t] = a;
    __syncthreads();
    for (int off = 128; off > 0; off >>= 1) {
        if (t < off) sm[t] += sm[t + off];
        __syncthreads();
    }
    if (t == 0)
        out[0] = sm[0] + (float)N_ATOMS * (float)N_ATOMS * b2[0];
}

extern "C" void kernel_launch(void* const* d_in, const int* in_sizes, int n_in,
                              void* d_out, int out_size, void* d_ws, size_t ws_size,
                              hipStream_t stream) {
    const float* h      = (const float*)d_in[0];
    const float* x      = (const float*)d_in[1];
    const float* W_fc   = (const float*)d_in[2];
    const float* W_edge = (const float*)d_in[3];
    const float* means  = (const float*)d_in[4];
    const float* betas  = (const float*)d_in[5];
    const float* W1     = (const float*)d_in[6];
    const float* b1     = (const float*)d_in[7];
    const float* W2     = (const float*)d_in[8];
    const float* b2     = (const float*)d_in[9];
    float* out = (float*)d_out;

    float* ws_partials = (float*)d_ws;                 // GRID_PAIR floats (pad 2560)
    float* ws_hp       = ws_partials + 2560;           // 1024*32
    float* ws_G        = ws_hp + N_ATOMS * H_DIM;      // TBL*32

    prep_kernel<<<160, 256, 0, stream>>>(h, W_fc, W_edge, means, betas, ws_hp, ws_G);
    pair_kernel<<<GRID_PAIR, 256, 0, stream>>>(x, ws_hp, ws_G, W1, b1, W2, ws_partials);
    reduce_kernel<<<1, 256, 0, stream>>>(ws_partials, b2, out);
}

// Round 5
// 25.816 us; speedup vs baseline: 3.3838x; 1.3364x over previous
//
#include <hip/hip_runtime.h>
#include <hip/hip_bf16.h>
#include <math.h>

#define N_ATOMS 1024
#define IN_F 64
#define H_DIM 32
#define NRBF 50
#define TILE 16
#define NT 64                 // tiles per dim
#define NBT 2080              // triangular tile count
#define TBL 4096              // bf16 G-table rows
#define SASTR 40              // LDS A row stride in bf16 elems (80B, 16B-aligned)

typedef short bf16x8 __attribute__((ext_vector_type(8)));
typedef float f32x4  __attribute__((ext_vector_type(4)));

static __device__ __forceinline__ unsigned short f2bf(float f) {
    unsigned int u = __float_as_uint(f);
    u += 0x7fffu + ((u >> 16) & 1u);     // RNE
    return (unsigned short)(u >> 16);
}
static __device__ __forceinline__ float bf2f(unsigned short u) {
    return __uint_as_float(((unsigned int)u) << 16);
}

// ---------------- Kernel 1: fused hp = h@W_fc AND bf16 G table --------------
__global__ __launch_bounds__(256) void prep_kernel(
    const float* __restrict__ h, const float* __restrict__ W_fc,
    const float* __restrict__ W_edge, const float* __restrict__ means,
    const float* __restrict__ betas, float* __restrict__ hp,
    unsigned short* __restrict__ Gb)
{
    const int blk = blockIdx.x;
    const int t = threadIdx.x;
    if (blk < 128) {                       // hp: 32768 threads
        int id = blk * 256 + t;
        int i = id >> 5, o = id & 31;
        float acc = 0.f;
        #pragma unroll 8
        for (int k = 0; k < IN_F; ++k)
            acc += h[i * IN_F + k] * W_fc[k * H_DIM + o];
        hp[i * H_DIM + o] = acc;
    } else {                               // table: 16384 threads (64 blocks)
        int id = (blk - 128) * 256 + t;
        int idx = id >> 2, c0 = (id & 3) * 8;
        float ed = (float)idx * (1.0f / (float)(TBL - 1));
        float acc[8];
        #pragma unroll
        for (int c = 0; c < 8; ++c) acc[c] = 0.f;
        for (int k = 0; k < NRBF; ++k) {   // uniform -> scalar loads
            float d = ed - means[k];
            float wv = __expf(-betas[k] * d * d);
            #pragma unroll
            for (int c = 0; c < 8; ++c)
                acc[c] += wv * W_edge[k * H_DIM + c0 + c];
        }
        bf16x8 pk;
        #pragma unroll
        for (int c = 0; c < 8; ++c) pk[c] = (short)f2bf(acc[c]);
        *(bf16x8*)&Gb[idx * H_DIM + c0] = pk;
    }
}

// ---------------- Kernel 2: one 16x16 pair tile per block -------------------
__global__ __launch_bounds__(256, 4) void pair_kernel(
    const float* __restrict__ x, const float* __restrict__ hp,
    const unsigned short* __restrict__ Gb, const float* __restrict__ W1,
    const float* __restrict__ b1, const float* __restrict__ W2,
    float* __restrict__ partials)
{
    __shared__ float sxi[TILE][4], sxj[TILE][4];
    __shared__ float shpi[TILE][36], shpj[TILE][36];
    __shared__ unsigned short sA[256 * SASTR];
    __shared__ float swave[4];

    const int t    = threadIdx.x;
    const int lane = t & 63;
    const int w    = t >> 6;
    const int c0f  = lane & 15;
    const int kb   = (lane >> 4) * 8;
    const int b    = blockIdx.x;

    // decode triangular tile (row-major upper triangle incl. diagonal)
    int ti = (int)(64.5f - sqrtf(64.5f * 64.5f - 2.0f * (float)b));
    ti = ti < 0 ? 0 : (ti > NT - 1 ? NT - 1 : ti);
    while ((ti + 1) * NT - ((ti + 1) * ti) / 2 <= b) ++ti;
    while (ti > 0 && ti * NT - (ti * (ti - 1)) / 2 > b) --ti;
    const int tj = ti + (b - (ti * NT - (ti * (ti - 1)) / 2));
    const int i0 = ti * TILE, j0 = tj * TILE;
    const float wgt = (ti == tj) ? 1.0f : 2.0f;

    // stage hp tiles (1 float4/thread) and x tiles
    if (t < 128) {
        int r = t >> 3, c = t & 7;
        *(float4*)&shpi[r][c * 4] = *(const float4*)&hp[(i0 + r) * H_DIM + c * 4];
    } else {
        int u = t - 128, r = u >> 3, c = u & 7;
        *(float4*)&shpj[r][c * 4] = *(const float4*)&hp[(j0 + r) * H_DIM + c * 4];
    }
    if (t < TILE) {
        sxi[t][0] = x[(i0 + t) * 3];
        sxi[t][1] = x[(i0 + t) * 3 + 1];
        sxi[t][2] = x[(i0 + t) * 3 + 2];
    } else if (t < 2 * TILE) {
        int u = t - TILE;
        sxj[u][0] = x[(j0 + u) * 3];
        sxj[u][1] = x[(j0 + u) * 3 + 1];
        sxj[u][2] = x[(j0 + u) * 3 + 2];
    }

    // hoisted W1/b1/W2 fragments (independent of staging)
    bf16x8 bfrag[2];
    float b1v[2], w2v[2];
    #pragma unroll
    for (int ct = 0; ct < 2; ++ct) {
        #pragma unroll
        for (int j = 0; j < 8; ++j)
            bfrag[ct][j] = (short)f2bf(W1[(kb + j) * H_DIM + c0f + 16 * ct]);
        b1v[ct] = b1[c0f + 16 * ct];
        w2v[ct] = W2[c0f + 16 * ct];
    }
    __syncthreads();

    const int li = t >> 4;
    const int lj = t & 15;

    const float dx = sxj[lj][0] - sxi[li][0];
    const float dy = sxj[lj][1] - sxi[li][1];
    const float dz = sxj[lj][2] - sxi[li][2];
    const float s  = dx * dx + dy * dy + dz * dz;

    const float dist = s + 1e-8f;
    const float dn2  = s / (s + 1e-8f);              // exactly 0 on diagonal
    const float sn   = __sinf(0.62831853f * dist);
    const float K    = dn2 * (sn * sn) * (sn * sn);  // dn2 * cut^2
    const float ed   = __expf(-dist);

    // nearest-neighbor bf16 table row: issue all 4 loads up-front
    float uu = ed * (float)(TBL - 1);
    int idx  = (int)(uu + 0.5f);
    if (idx > TBL - 1) idx = TBL - 1;
    const unsigned short* __restrict__ r0 = Gb + idx * H_DIM;
    bf16x8 g0 = *(const bf16x8*)(r0);
    bf16x8 g1 = *(const bf16x8*)(r0 + 8);
    bf16x8 g2 = *(const bf16x8*)(r0 + 16);
    bf16x8 g3 = *(const bf16x8*)(r0 + 24);

    // ese = hp_i + hp_j into registers (overlaps with G-load latency)
    f32x4 ese[8];
    #pragma unroll
    for (int q = 0; q < 8; ++q) {
        float4 hi = *(const float4*)&shpi[li][q * 4];
        float4 hj = *(const float4*)&shpj[lj][q * 4];
        ese[q][0] = hi.x + hj.x;
        ese[q][1] = hi.y + hj.y;
        ese[q][2] = hi.z + hj.z;
        ese[q][3] = hi.w + hj.w;
    }

    // cnorm = (ese * g)^2 * K -> bf16 -> swizzled LDS
    const int sw = (t >> 3) & 3;
    {
        bf16x8 gs[4] = {g0, g1, g2, g3};
        #pragma unroll
        for (int q = 0; q < 4; ++q) {
            bf16x8 pk;
            #pragma unroll
            for (int j = 0; j < 8; ++j) {
                float v = bf2f((unsigned short)gs[q][j]) * ese[q * 2 + (j >> 2)][j & 3];
                pk[j] = (short)f2bf(v * v * K);
            }
            *(bf16x8*)&sA[t * SASTR + (q ^ sw) * 8] = pk;
        }
    }
    __syncthreads();

    // MFMA: a = cnorm @ W1 ; epilogue sigmoid/W2
    float p = 0.f;
    #pragma unroll
    for (int rt = 0; rt < 4; ++rt) {
        const int row = w * 64 + rt * 16 + c0f;
        const int rq  = (lane >> 4) ^ ((row >> 3) & 3);   // un-swizzle
        bf16x8 afrag = *(const bf16x8*)&sA[row * SASTR + rq * 8];
        #pragma unroll
        for (int ct = 0; ct < 2; ++ct) {
            f32x4 acc = {0.f, 0.f, 0.f, 0.f};
            acc = __builtin_amdgcn_mfma_f32_16x16x32_bf16(afrag, bfrag[ct], acc, 0, 0, 0);
            #pragma unroll
            for (int r = 0; r < 4; ++r) {
                const float av = acc[r] + b1v[ct];
                p += w2v[ct] * __builtin_amdgcn_rcpf(1.0f + __expf(-av));
            }
        }
    }

    // block reduction (deterministic)
    float v = wgt * p;
    #pragma unroll
    for (int off = 32; off > 0; off >>= 1)
        v += __shfl_down(v, off);
    if (lane == 0) swave[w] = v;
    __syncthreads();
    if (t == 0)
        partials[b] = (swave[0] + swave[1]) + (swave[2] + swave[3]);
}

// ---------------- Kernel 3: final deterministic reduction -------------------
__global__ __launch_bounds__(256) void reduce_kernel(
    const float* __restrict__ partials, const float* __restrict__ b2,
    float* __restrict__ out)
{
    __shared__ float sm[256];
    const int t = threadIdx.x;
    float a = 0.f;
    for (int u = t; u < NBT; u += 256) a += partials[u];
    sm[t] = a;
    __syncthreads();
    for (int off = 128; off > 0; off >>= 1) {
        if (t < off) sm[t] += sm[t + off];
        __syncthreads();
    }
    if (t == 0)
        out[0] = sm[0] + (float)N_ATOMS * (float)N_ATOMS * b2[0];
}

extern "C" void kernel_launch(void* const* d_in, const int* in_sizes, int n_in,
                              void* d_out, int out_size, void* d_ws, size_t ws_size,
                              hipStream_t stream) {
    const float* h      = (const float*)d_in[0];
    const float* x      = (const float*)d_in[1];
    const float* W_fc   = (const float*)d_in[2];
    const float* W_edge = (const float*)d_in[3];
    const float* means  = (const float*)d_in[4];
    const float* betas  = (const float*)d_in[5];
    const float* W1     = (const float*)d_in[6];
    const float* b1     = (const float*)d_in[7];
    const float* W2     = (const float*)d_in[8];
    const float* b2     = (const float*)d_in[9];
    float* out = (float*)d_out;

    float*          ws_partials = (float*)d_ws;              // NBT floats (pad 2560)
    float*          ws_hp       = ws_partials + 2560;        // 1024*32 floats
    unsigned short* ws_Gb       = (unsigned short*)(ws_hp + N_ATOMS * H_DIM);  // TBL*32 bf16

    prep_kernel<<<192, 256, 0, stream>>>(h, W_fc, W_edge, means, betas, ws_hp, ws_Gb);
    pair_kernel<<<NBT, 256, 0, stream>>>(x, ws_hp, ws_Gb, W1, b1, W2, ws_partials);
    reduce_kernel<<<1, 256, 0, stream>>>(ws_partials, b2, out);
}

// Round 6
// 24.218 us; speedup vs baseline: 3.6071x; 1.0660x over previous
//
#include <hip/hip_runtime.h>
#include <hip/hip_bf16.h>
#include <math.h>

#define N_ATOMS 1024
#define IN_F 64
#define H_DIM 32
#define NRBF 50
#define TILE 16
#define NT 64
#define NBT 2080
#define TBL 4096
#define SASTR 40              // LDS A row stride (bf16 elems), 80B rows

typedef short bf16x8 __attribute__((ext_vector_type(8)));
typedef float f32x4  __attribute__((ext_vector_type(4)));

static __device__ __forceinline__ unsigned short f2bf(float f) {
    unsigned int u = __float_as_uint(f);
    u += 0x7fffu + ((u >> 16) & 1u);     // RNE (prep only)
    return (unsigned short)(u >> 16);
}

// ---- Kernel 1: hp = h@W_fc, bf16 G table, W1 fragments, bw, tile table -----
__global__ __launch_bounds__(256) void prep_kernel(
    const float* __restrict__ h, const float* __restrict__ W_fc,
    const float* __restrict__ W_edge, const float* __restrict__ means,
    const float* __restrict__ betas, const float* __restrict__ W1,
    const float* __restrict__ b1, const float* __restrict__ W2,
    float* __restrict__ hp, unsigned short* __restrict__ Gb,
    unsigned short* __restrict__ Wp, float2* __restrict__ bw,
    int* __restrict__ tt)
{
    const int blk = blockIdx.x;
    const int t = threadIdx.x;
    if (blk < 128) {                       // hp
        int id = blk * 256 + t;
        int i = id >> 5, o = id & 31;
        float acc = 0.f;
        #pragma unroll 8
        for (int k = 0; k < IN_F; ++k)
            acc += h[i * IN_F + k] * W_fc[k * H_DIM + o];
        hp[i * H_DIM + o] = acc;
    } else if (blk < 192) {                // G table (bf16, nearest-neighbor)
        int id = (blk - 128) * 256 + t;
        int idx = id >> 2, c0 = (id & 3) * 8;
        float ed = (float)idx * (1.0f / (float)(TBL - 1));
        float acc[8];
        #pragma unroll
        for (int c = 0; c < 8; ++c) acc[c] = 0.f;
        for (int k = 0; k < NRBF; ++k) {
            float d = ed - means[k];
            float wv = __expf(-betas[k] * d * d);
            #pragma unroll
            for (int c = 0; c < 8; ++c)
                acc[c] += wv * W_edge[k * H_DIM + c0 + c];
        }
        bf16x8 pk;
        #pragma unroll
        for (int c = 0; c < 8; ++c) pk[c] = (short)f2bf(acc[c]);
        *(bf16x8*)&Gb[idx * H_DIM + c0] = pk;
    } else if (blk < 201) {                // triangular tile table
        int e = (blk - 192) * 256 + t;
        if (e < NBT) {
            int ti = (int)(64.5f - sqrtf(64.5f * 64.5f - 2.0f * (float)e));
            ti = ti < 0 ? 0 : (ti > NT - 1 ? NT - 1 : ti);
            while ((ti + 1) * NT - ((ti + 1) * ti) / 2 <= e) ++ti;
            while (ti > 0 && ti * NT - (ti * (ti - 1)) / 2 > e) --ti;
            int tj = ti + (e - (ti * NT - (ti * (ti - 1)) / 2));
            tt[e] = (ti << 8) | tj;
        }
    } else {                               // W1 fragments + bw
        #pragma unroll
        for (int q = 0; q < 4; ++q) {
            int f  = t * 4 + q;            // f = ct*512 + lane*8 + j
            int ct = f >> 9, ln = (f >> 3) & 63, j = f & 7;
            int c0f = ln & 15, kb = (ln >> 4) * 8;
            Wp[f] = f2bf(W1[(kb + j) * H_DIM + c0f + 16 * ct]);
        }
        if (t < 32) { float2 v; v.x = b1[t]; v.y = W2[t]; bw[t] = v; }
    }
}

// ---- Kernel 2: one 16x16 pair tile per block -------------------------------
__global__ __launch_bounds__(256, 6) void pair_kernel(
    const float* __restrict__ x, const float* __restrict__ hp,
    const unsigned short* __restrict__ Gb, const unsigned short* __restrict__ Wp,
    const float2* __restrict__ bw, const int* __restrict__ tt,
    float* __restrict__ partials)
{
    __shared__ float shpi[TILE][36], shpj[TILE][36];
    __shared__ unsigned short sA[256 * SASTR];
    __shared__ float swave[4];

    const int t    = threadIdx.x;
    const int lane = t & 63;
    const int w    = t >> 6;
    const int c0f  = lane & 15;
    const int b    = blockIdx.x;

    const int tv = tt[b];                  // uniform -> s_load
    const int ti = tv >> 8, tj = tv & 255;
    const int i0 = ti * TILE, j0 = tj * TILE;
    const float wgt = (ti == tj) ? 1.0f : 2.0f;

    const int li = t >> 4;
    const int lj = t & 15;

    // x coords direct from global (L1-hot), issues immediately
    const float xi0 = x[(i0 + li) * 3 + 0];
    const float xi1 = x[(i0 + li) * 3 + 1];
    const float xi2 = x[(i0 + li) * 3 + 2];
    const float xj0 = x[(j0 + lj) * 3 + 0];
    const float xj1 = x[(j0 + lj) * 3 + 1];
    const float xj2 = x[(j0 + lj) * 3 + 2];

    // stage hp tiles: 1 float4 per thread
    if (t < 128) {
        int r = t >> 3, c = t & 7;
        *(float4*)&shpi[r][c * 4] = *(const float4*)&hp[(i0 + r) * H_DIM + c * 4];
    } else {
        int u = t - 128, r = u >> 3, c = u & 7;
        *(float4*)&shpj[r][c * 4] = *(const float4*)&hp[(j0 + r) * H_DIM + c * 4];
    }

    // pre-packed W1 fragments + bias/W2
    bf16x8 bfrag0 = *(const bf16x8*)&Wp[lane * 8];
    bf16x8 bfrag1 = *(const bf16x8*)&Wp[512 + lane * 8];
    const float2 bw0 = bw[c0f];
    const float2 bw1 = bw[c0f + 16];

    // distance / cutoff / table index
    const float dx = xj0 - xi0, dy = xj1 - xi1, dz = xj2 - xi2;
    const float s  = dx * dx + dy * dy + dz * dz;
    const float dist = s + 1e-8f;
    const float dn2  = s / (s + 1e-8f);              // exactly 0 on diagonal
    const float sn   = __sinf(0.62831853f * dist);
    const float K    = dn2 * (sn * sn) * (sn * sn);  // dn2 * cut^2
    const float ed   = __expf(-dist);

    float uu = ed * (float)(TBL - 1);
    int idx  = (int)(uu + 0.5f);
    if (idx > TBL - 1) idx = TBL - 1;
    const unsigned short* __restrict__ r0 = Gb + idx * H_DIM;
    const bf16x8 gA = *(const bf16x8*)(r0);
    const bf16x8 gB = *(const bf16x8*)(r0 + 8);
    const bf16x8 gC = *(const bf16x8*)(r0 + 16);
    const bf16x8 gD = *(const bf16x8*)(r0 + 24);

    __syncthreads();                       // hp tiles visible

    // cnorm = ((hp_i+hp_j)*g)^2 * K -> bf16 (round-half-up) -> swizzled LDS
    const int sw = (t >> 3) & 3;
    #pragma unroll
    for (int q = 0; q < 4; ++q) {
        const bf16x8 gs = (q == 0) ? gA : (q == 1) ? gB : (q == 2) ? gC : gD;
        union { bf16x8 v8; unsigned int u[4]; } gu, pk;
        gu.v8 = gs;
        const float4 hi0 = *(const float4*)&shpi[li][q * 8];
        const float4 hi1 = *(const float4*)&shpi[li][q * 8 + 4];
        const float4 hj0 = *(const float4*)&shpj[lj][q * 8];
        const float4 hj1 = *(const float4*)&shpj[lj][q * 8 + 4];
        float e0 = hi0.x + hj0.x, e1 = hi0.y + hj0.y;
        float e2 = hi0.z + hj0.z, e3 = hi0.w + hj0.w;
        float e4 = hi1.x + hj1.x, e5 = hi1.y + hj1.y;
        float e6 = hi1.z + hj1.z, e7 = hi1.w + hj1.w;
        float g0 = __uint_as_float(gu.u[0] << 16);
        float g1 = __uint_as_float(gu.u[0] & 0xffff0000u);
        float g2 = __uint_as_float(gu.u[1] << 16);
        float g3 = __uint_as_float(gu.u[1] & 0xffff0000u);
        float g4 = __uint_as_float(gu.u[2] << 16);
        float g5 = __uint_as_float(gu.u[2] & 0xffff0000u);
        float g6 = __uint_as_float(gu.u[3] << 16);
        float g7 = __uint_as_float(gu.u[3] & 0xffff0000u);
        float v0 = e0 * g0, v1 = e1 * g1, v2 = e2 * g2, v3 = e3 * g3;
        float v4 = e4 * g4, v5 = e5 * g5, v6 = e6 * g6, v7 = e7 * g7;
        float c0 = v0 * v0 * K, c1 = v1 * v1 * K, c2 = v2 * v2 * K, c3 = v3 * v3 * K;
        float c4 = v4 * v4 * K, c5 = v5 * v5 * K, c6 = v6 * v6 * K, c7 = v7 * v7 * K;
        pk.u[0] = ((__float_as_uint(c0) + 0x8000u) >> 16) | ((__float_as_uint(c1) + 0x8000u) & 0xffff0000u);
        pk.u[1] = ((__float_as_uint(c2) + 0x8000u) >> 16) | ((__float_as_uint(c3) + 0x8000u) & 0xffff0000u);
        pk.u[2] = ((__float_as_uint(c4) + 0x8000u) >> 16) | ((__float_as_uint(c5) + 0x8000u) & 0xffff0000u);
        pk.u[3] = ((__float_as_uint(c6) + 0x8000u) >> 16) | ((__float_as_uint(c7) + 0x8000u) & 0xffff0000u);
        *(bf16x8*)&sA[t * SASTR + (q ^ sw) * 8] = pk.v8;
    }
    __syncthreads();

    // MFMA: a = cnorm @ W1 ; epilogue sigmoid/W2
    float p = 0.f;
    #pragma unroll
    for (int rt = 0; rt < 4; ++rt) {
        const int row = w * 64 + rt * 16 + c0f;
        const int rq  = (lane >> 4) ^ ((row >> 3) & 3);
        bf16x8 afrag = *(const bf16x8*)&sA[row * SASTR + rq * 8];
        f32x4 acc0 = {0.f, 0.f, 0.f, 0.f};
        acc0 = __builtin_amdgcn_mfma_f32_16x16x32_bf16(afrag, bfrag0, acc0, 0, 0, 0);
        f32x4 acc1 = {0.f, 0.f, 0.f, 0.f};
        acc1 = __builtin_amdgcn_mfma_f32_16x16x32_bf16(afrag, bfrag1, acc1, 0, 0, 0);
        #pragma unroll
        for (int r = 0; r < 4; ++r) {
            const float av0 = acc0[r] + bw0.x;
            p += bw0.y * __builtin_amdgcn_rcpf(1.0f + __expf(-av0));
            const float av1 = acc1[r] + bw1.x;
            p += bw1.y * __builtin_amdgcn_rcpf(1.0f + __expf(-av1));
        }
    }

    // block reduction (deterministic)
    float v = wgt * p;
    #pragma unroll
    for (int off = 32; off > 0; off >>= 1)
        v += __shfl_down(v, off);
    if (lane == 0) swave[w] = v;
    __syncthreads();
    if (t == 0)
        partials[b] = (swave[0] + swave[1]) + (swave[2] + swave[3]);
}

// ---- Kernel 3: final deterministic reduction -------------------------------
__global__ __launch_bounds__(256) void reduce_kernel(
    const float* __restrict__ partials, const float* __restrict__ b2,
    float* __restrict__ out)
{
    __shared__ float sm[256];
    const int t = threadIdx.x;
    float a = 0.f;
    for (int u = t; u < NBT; u += 256) a += partials[u];
    sm[t] = a;
    __syncthreads();
    for (int off = 128; off > 0; off >>= 1) {
        if (t < off) sm[t] += sm[t + off];
        __syncthreads();
    }
    if (t == 0)
        out[0] = sm[0] + (float)N_ATOMS * (float)N_ATOMS * b2[0];
}

extern "C" void kernel_launch(void* const* d_in, const int* in_sizes, int n_in,
                              void* d_out, int out_size, void* d_ws, size_t ws_size,
                              hipStream_t stream) {
    const float* h      = (const float*)d_in[0];
    const float* x      = (const float*)d_in[1];
    const float* W_fc   = (const float*)d_in[2];
    const float* W_edge = (const float*)d_in[3];
    const float* means  = (const float*)d_in[4];
    const float* betas  = (const float*)d_in[5];
    const float* W1     = (const float*)d_in[6];
    const float* b1     = (const float*)d_in[7];
    const float* W2     = (const float*)d_in[8];
    const float* b2     = (const float*)d_in[9];
    float* out = (float*)d_out;

    char* base = (char*)d_ws;
    float*          ws_partials = (float*)base;                    // 2560 f
    float*          ws_hp       = (float*)(base + 10240);          // 1024*32 f
    unsigned short* ws_Gb       = (unsigned short*)(base + 141312);// TBL*32 bf16
    unsigned short* ws_Wp       = (unsigned short*)(base + 403456);// 1024 bf16
    float2*         ws_bw       = (float2*)(base + 405504);        // 32 float2
    int*            ws_tt       = (int*)(base + 405760);           // 2080 int

    prep_kernel<<<202, 256, 0, stream>>>(h, W_fc, W_edge, means, betas,
                                         W1, b1, W2, ws_hp, ws_Gb, ws_Wp,
                                         ws_bw, ws_tt);
    pair_kernel<<<NBT, 256, 0, stream>>>(x, ws_hp, ws_Gb, ws_Wp, ws_bw,
                                         ws_tt, ws_partials);
    reduce_kernel<<<1, 256, 0, stream>>>(ws_partials, b2, out);
}